// Round 9
// baseline (192.812 us; speedup 1.0000x reference)
//
#include <hip/hip_runtime.h>

#define B_SZ   4
#define T_LEN  2048
#define C_DIM  768
#define H_NUM  12
#define THREEC (3 * C_DIM)
#define M_ROWS (B_SZ * T_LEN)          // 8192
#define CAST_N8 (M_ROWS * C_DIM / 8)   // 786432
#define CAST_BLOCKS (CAST_N8 / 256)    // 3072
#define TP_BX ((THREEC + C_DIM) / 32)  // 96
#define TP_BY (C_DIM / 32)             // 24

typedef _Float16 f16;
typedef _Float16 half8 __attribute__((ext_vector_type(8)));
typedef _Float16 half4 __attribute__((ext_vector_type(4)));
typedef __fp16   pk2   __attribute__((ext_vector_type(2)));
typedef float    f32x4 __attribute__((ext_vector_type(4)));

// async global->LDS, 16B/lane; LDS dest = wave-uniform base + lane*16
#define GLD16(gaddr, laddr)                                                         \
  __builtin_amdgcn_global_load_lds(                                                 \
      (const __attribute__((address_space(1))) unsigned int*)(gaddr),               \
      (__attribute__((address_space(3))) unsigned int*)(laddr), 16, 0, 0)
#define MFMA16(a, b, c) __builtin_amdgcn_mfma_f32_16x16x32_f16(a, b, c, 0, 0, 0)

// ---------------------------------------------------------------------------
// Fused prep: [blocks 0..3071] cast x fp32->fp16 (8 elems/thread);
// [blocks 3072..5375] W_attn/W_proj transpose-cast W[K][N] fp32 -> Wt[N][K].
// ---------------------------------------------------------------------------
__global__ __launch_bounds__(256) void prep_kernel(
    const float* __restrict__ x, f16* __restrict__ xh,
    const float* __restrict__ Wa, const float* __restrict__ Wp,
    f16* __restrict__ WtA, f16* __restrict__ WtP) {
  __shared__ f16 tile[32][33];
  const int bid = blockIdx.x;
  if (bid < CAST_BLOCKS) {
    int i = bid * 256 + threadIdx.x;
    const float* s = x + (size_t)i * 8;
    half8 h;
#pragma unroll
    for (int u = 0; u < 8; ++u) h[u] = (f16)s[u];
    *(half8*)(xh + (size_t)i * 8) = h;
    return;   // block-uniform branch; these blocks never reach the barrier
  }
  const int t = bid - CAST_BLOCKS;
  int bx = t % TP_BX;
  const int by = t / TP_BX;
  const float* W; f16* Wt; int N;
  if (bx < THREEC / 32) { W = Wa; Wt = WtA; N = THREEC; }
  else { W = Wp; Wt = WtP; N = C_DIM; bx -= THREEC / 32; }
  const int n0 = bx * 32, k0 = by * 32;
  const int tx = threadIdx.x & 31, ty = threadIdx.x >> 5;
#pragma unroll
  for (int i = 0; i < 4; ++i)
    tile[ty + i * 8][tx] = (f16)W[(size_t)(k0 + ty + i * 8) * N + n0 + tx];
  __syncthreads();
#pragma unroll
  for (int i = 0; i < 4; ++i)
    Wt[(size_t)(n0 + ty + i * 8) * C_DIM + k0 + tx] = tile[tx][ty + i * 8];
}

// ---------------------------------------------------------------------------
// MFMA GEMM: C[M][N] = A[M][K] @ Bt[N][K]^T + bias.
// Round 9: counted-vmcnt double-buffer (the attn-proven structure). The old
// loop's __syncthreads after staging drained vmcnt(0) every K-iteration --
// 12 fully-exposed ~400cy stage stalls/block (MFMA floor 3.6us vs 44us
// measured, nothing saturated = latency-bound). New: BK=32, As/Bs[2][] dbuf
// (LDS stays 32KB -> occupancy preserved, r7 lesson), stage(it+1) issued
// BEFORE compute(it), s_waitcnt vmcnt(#inflight) + raw s_barrier. Chunk-XOR
// swizzle re-derived for 4-chunk rows: source cc = (c&3)^((r>>1)&3), read
// chunk = kq^((lm>>1)&3) -- same uniform 8-lane/bank-quad spread as the
// proven BK=64 layout. 4 waves 2x2, XCD chunked swizzle kept.
// ---------------------------------------------------------------------------
template <int BM, int BN, int OUT_F16, int SWZ>
__global__ __launch_bounds__(256) void gemm_f16_kernel(
    const f16* __restrict__ A, const f16* __restrict__ Bt,
    const float* __restrict__ bias, f16* __restrict__ OutH,
    float* __restrict__ OutF, int M, int N, int K) {
  __shared__ f16 As[2][BM * 32];
  __shared__ f16 Bs[2][BN * 32];
  const int tid = threadIdx.x;
  const int lane = tid & 63, wave = tid >> 6;
  const int lm = lane & 15, kq = lane >> 4;
  const int lmx = (lm >> 1) & 3;            // read-side chunk XOR
  const int rchunk = (kq ^ lmx) * 8;        // f16 offset of this lane's chunk
  constexpr int MT = BM / 32, NT = BN / 32;
  const int wm = (wave & 1) * (BM / 2), wn = (wave >> 1) * (BN / 2);

  int bx = blockIdx.x, by = blockIdx.y;
  if (SWZ) {
    const int nx = gridDim.x;
    const int lin = by * nx + bx;
    const int cpx = (nx * gridDim.y) >> 3;     // blocks per XCD chunk
    const int swz = (lin & 7) * cpx + (lin >> 3);
    bx = swz % nx;
    by = swz / nx;
  }
  const int row0 = by * BM, col0 = bx * BN;

  f32x4 acc[MT][NT] = {};

  // stage K-tile kt (32 wide) into buffer buf
  auto stage = [&](int kt, int buf) {
    const int kof = kt * 32;
#pragma unroll
    for (int i = 0; i < BM / 64; ++i) {
      int c = tid + i * 256;
      int r = c >> 2, cc = (c & 3) ^ ((r >> 1) & 3);
      GLD16(&A[(size_t)(row0 + r) * K + kof + cc * 8],
            &As[buf][(i * 256 + wave * 64) * 8]);
    }
#pragma unroll
    for (int i = 0; i < BN / 64; ++i) {
      int c = tid + i * 256;
      int r = c >> 2, cc = (c & 3) ^ ((r >> 1) & 3);
      GLD16(&Bt[(size_t)(col0 + r) * K + kof + cc * 8],
            &Bs[buf][(i * 256 + wave * 64) * 8]);
    }
  };

  const int nk = K >> 5;
  stage(0, 0);
  for (int kt = 0; kt < nk; ++kt) {
    const int cur = kt & 1;
    if (kt + 1 < nk) {
      stage(kt + 1, cur ^ 1);
      // wait for tile kt's loads; tile kt+1's stay in flight (T4)
      if constexpr ((BM + BN) / 64 == 4)
        asm volatile("s_waitcnt vmcnt(4)" ::: "memory");
      else
        asm volatile("s_waitcnt vmcnt(3)" ::: "memory");
    } else {
      asm volatile("s_waitcnt vmcnt(0)" ::: "memory");
    }
    __builtin_amdgcn_s_barrier();   // stage(kt) visible to all waves

    half8 af[MT], bf[NT];
#pragma unroll
    for (int t = 0; t < MT; ++t)
      af[t] = *(const half8*)&As[cur][(wm + t * 16 + lm) * 32 + rchunk];
#pragma unroll
    for (int t = 0; t < NT; ++t)
      bf[t] = *(const half8*)&Bs[cur][(wn + t * 16 + lm) * 32 + rchunk];
#pragma unroll
    for (int mt = 0; mt < MT; ++mt)
#pragma unroll
      for (int nt = 0; nt < NT; ++nt)
        acc[mt][nt] = MFMA16(af[mt], bf[nt], acc[mt][nt]);

    // all waves done reading buf cur before next iter's stage overwrites it
    __builtin_amdgcn_s_barrier();
  }

#pragma unroll
  for (int mt = 0; mt < MT; ++mt) {
    const int row = row0 + wm + mt * 16 + kq * 4;
#pragma unroll
    for (int nt = 0; nt < NT; ++nt) {
      const int col = col0 + wn + nt * 16 + lm;
      const float bv = bias[col];
#pragma unroll
      for (int r = 0; r < 4; ++r) {
        float v = acc[mt][nt][r] + bv;
        if (OUT_F16)
          OutH[(size_t)(row + r) * N + col] = (f16)v;
        else
          OutF[(size_t)(row + r) * N + col] = v;
      }
    }
  }
}

// ---------------------------------------------------------------------------
// V pre-transpose: qkv[B*T][3C] (V slice) -> vt[bh][d=64][T] f16, with the
// tau key-permutation applied within each 64-key block:
//   vt[d][64*blk + m] = V[64*blk + tau(m)][d],
//   tau(m): m bits (hi,kq,j23,j01) -> key = 32*hi + 16*j23 + 4*kq + j01.
// Makes the attention QK^T C-layout directly usable as the PV A-fragment.
// ---------------------------------------------------------------------------
__global__ __launch_bounds__(256) void v_transpose_kernel(
    const f16* __restrict__ qkv, f16* __restrict__ vt) {
  __shared__ f16 tile[64 * 68];
  const int bh = blockIdx.x, b = bh / H_NUM, h = bh % H_NUM;
  const int t0 = blockIdx.y * 64;
  const int tid = threadIdx.x;
#pragma unroll
  for (int i = 0; i < 2; ++i) {
    int c = tid + i * 256;
    int tr = c >> 3, doff = (c & 7) * 8;
    // tau_inv(tr): key bits (hi,j23,kq,j01) -> m = 32*hi + 8*kq + 4*j23 + j01
    int pcol = ((tr >> 5) << 5) | (((tr >> 2) & 3) << 3) |
               (((tr >> 4) & 1) << 2) | (tr & 3);
    half8 v = *(const half8*)&qkv[(size_t)(b * T_LEN + t0 + tr) * THREEC + 2 * C_DIM + h * 64 + doff];
#pragma unroll
    for (int u = 0; u < 8; ++u) tile[(doff + u) * 68 + pcol] = v[u];
  }
  __syncthreads();
#pragma unroll
  for (int i = 0; i < 2; ++i) {
    int c = tid + i * 256;
    int d = c >> 3, toff = (c & 7) * 8;
    half8 v;
#pragma unroll
    for (int u = 0; u < 8; ++u) v[u] = tile[d * 68 + toff + u];
    *(half8*)&vt[((size_t)bh * 64 + d) * T_LEN + t0 + toff] = v;
  }
}

// ---------------------------------------------------------------------------
// MFMA causal flash attention, S^T formulation, XOR-swizzled LDS, no-max
// softmax, l via ones-MFMA, in-register P via tau-permuted V.
// r8-proven: 4 waves x 32 q each (cq=2), dbuf K/V staging with counted
// vmcnt(4), 2 barriers/iter, grid 768 = 3 blocks/CU. Unchanged this round.
// ---------------------------------------------------------------------------
__global__ __launch_bounds__(256, 3) void attn_kernel(
    const f16* __restrict__ qkv, const f16* __restrict__ vt,
    f16* __restrict__ y) {
  __shared__ f16 Kt[2][64 * 64];   // [buf][key][d], swizzled
  __shared__ f16 Vt[2][64 * 64];   // [buf][d][key-pos], swizzled, tau-permuted

  const int bh = blockIdx.x, b = bh / H_NUM, h = bh % H_NUM;
  const int yb = blockIdx.y;                 // 0..15, heavy-first
  const int qb = 15 - yb;                    // q-block: rows [qb*128, qb*128+128)
  const int tid = threadIdx.x, lane = tid & 63, wave = tid >> 6;  // wave 0..3
  const int lm = lane & 15, kq = lane >> 4, lm7 = lm & 7;
  const int cw = qb * 2 + (wave >> 1);       // last key-tile this wave needs
  const int qw = qb * 128 + wave * 32;       // wave's 32 q-rows
  const f16 qscale = (f16)(0.125f * 1.44269504f);  // 1/sqrt(D) * log2(e)

  half8 vones;
#pragma unroll
  for (int u = 0; u < 8; ++u) vones[u] = (f16)1.f;

  // Q B-frags: bq[cq][c2], q = qw + cq*16 + lm (pre-scaled). The multiply
  // forces the vmcnt wait HERE, before any staging GLDs are issued.
  half8 bq[2][2];
#pragma unroll
  for (int cq = 0; cq < 2; ++cq)
#pragma unroll
    for (int c2 = 0; c2 < 2; ++c2) {
      half8 v = *(const half8*)&qkv[(size_t)(b * T_LEN + qw + cq * 16 + lm) * THREEC +
                                    h * 64 + c2 * 32 + kq * 8];
      bq[cq][c2] = v * qscale;
    }

  f32x4 o[4][2] = {};   // o[dt][cq]: col = d (lm), row = q (kq*4+r)
  f32x4 ol[2] = {};     // l accumulators, same row layout

  // persistent zero C-operand for the S^T MFMAs (avoid per-tile v_movs)
  f32x4 fz = {};
  asm volatile("" : "+v"(fz));

  // staging geometry: 2 K-chunks + 2 V-chunks per thread (16B each)
  const int srow = tid >> 3;                          // 0..31
  const int scol = ((tid & 7) ^ (srow & 7)) * 8;      // same for srow+32
  const f16* kp = &qkv[(size_t)(b * T_LEN + srow) * THREEC + C_DIM + h * 64 + scol];
  const f16* vp = &vt[((size_t)bh * 64 + srow) * T_LEN + scol];
  const size_t kp2 = (size_t)32 * THREEC;             // +32 rows
  const size_t vp2 = (size_t)32 * T_LEN;

  const int sbase = wave * 512;   // f16 offset of this wave's staging slice

  const int n_tiles = qb * 2 + 2;

  // prologue: stage tile 0 into buf 0 (rows 0..31 then 32..63 of each)
  GLD16(kp, &Kt[0][sbase]);
  GLD16(kp + kp2, &Kt[0][2048 + sbase]);
  GLD16(vp, &Vt[0][sbase]);
  GLD16(vp + vp2, &Vt[0][2048 + sbase]);
  kp += (size_t)64 * THREEC;
  vp += 64;

  for (int it = 0; it < n_tiles; ++it) {
    const int cur = it & 1;
    // stage tile it+1 into buf cur^1 (freed by barrier #2 of iter it-1)
    if (it + 1 < n_tiles) {
      GLD16(kp, &Kt[cur ^ 1][sbase]);
      GLD16(kp + kp2, &Kt[cur ^ 1][2048 + sbase]);
      GLD16(vp, &Vt[cur ^ 1][sbase]);
      GLD16(vp + vp2, &Vt[cur ^ 1][2048 + sbase]);
      kp += (size_t)64 * THREEC;
      vp += 64;
      // wait for tile it's 4 loads (oldest); it+1's 4 stay in flight
      asm volatile("s_waitcnt vmcnt(4)" ::: "memory");
    } else {
      asm volatile("s_waitcnt vmcnt(0)" ::: "memory");
    }
    __builtin_amdgcn_s_barrier();   // all waves' stage(it) visible

    if (it <= cw) {
      // S^T = K @ Q^T : A = K rows (keys), B = Q -> col = q, row = key
      f32x4 s4[4][2];
#pragma unroll
      for (int ct = 0; ct < 4; ++ct) {
        const f16* kr = &Kt[cur][(ct * 16 + lm) * 64];
        half8 ak0 = *(const half8*)&kr[(kq ^ lm7) * 8];
        half8 ak1 = *(const half8*)&kr[((4 + kq) ^ lm7) * 8];
#pragma unroll
        for (int cq = 0; cq < 2; ++cq) {
          f32x4 z = MFMA16(ak0, bq[cq][0], fz);
          s4[ct][cq] = MFMA16(ak1, bq[cq][1], z);
        }
      }
      if (it == cw) {   // diagonal tile: mask keys > q
        const int j0 = it * 64;
#pragma unroll
        for (int ct = 0; ct < 4; ++ct)
#pragma unroll
          for (int cq = 0; cq < 2; ++cq) {
            const int qrow = qw + cq * 16 + lm;
#pragma unroll
            for (int r = 0; r < 4; ++r)
              if (j0 + ct * 16 + kq * 4 + r > qrow) s4[ct][cq][r] = -1e30f;
          }
      }
      // p = exp2(s), packed f32->f16 (RTZ), IN REGISTERS per cq group.
      union { half8 h8; pk2 p2[4]; } pa0[2], pa1[2];
#pragma unroll
      for (int cq = 0; cq < 2; ++cq) {
        pa0[cq].p2[0] = __builtin_amdgcn_cvt_pkrtz(
            __builtin_amdgcn_exp2f(s4[0][cq][0]), __builtin_amdgcn_exp2f(s4[0][cq][1]));
        pa0[cq].p2[1] = __builtin_amdgcn_cvt_pkrtz(
            __builtin_amdgcn_exp2f(s4[0][cq][2]), __builtin_amdgcn_exp2f(s4[0][cq][3]));
        pa0[cq].p2[2] = __builtin_amdgcn_cvt_pkrtz(
            __builtin_amdgcn_exp2f(s4[1][cq][0]), __builtin_amdgcn_exp2f(s4[1][cq][1]));
        pa0[cq].p2[3] = __builtin_amdgcn_cvt_pkrtz(
            __builtin_amdgcn_exp2f(s4[1][cq][2]), __builtin_amdgcn_exp2f(s4[1][cq][3]));
        pa1[cq].p2[0] = __builtin_amdgcn_cvt_pkrtz(
            __builtin_amdgcn_exp2f(s4[2][cq][0]), __builtin_amdgcn_exp2f(s4[2][cq][1]));
        pa1[cq].p2[1] = __builtin_amdgcn_cvt_pkrtz(
            __builtin_amdgcn_exp2f(s4[2][cq][2]), __builtin_amdgcn_exp2f(s4[2][cq][3]));
        pa1[cq].p2[2] = __builtin_amdgcn_cvt_pkrtz(
            __builtin_amdgcn_exp2f(s4[3][cq][0]), __builtin_amdgcn_exp2f(s4[3][cq][1]));
        pa1[cq].p2[3] = __builtin_amdgcn_cvt_pkrtz(
            __builtin_amdgcn_exp2f(s4[3][cq][2]), __builtin_amdgcn_exp2f(s4[3][cq][3]));
      }

      // PV: O += P @ V^T ; l: ol += P @ 1  (V frags shared across cq)
#pragma unroll
      for (int dt = 0; dt < 4; ++dt) {
        const f16* vr = &Vt[cur][(dt * 16 + lm) * 64];
        half8 bv0 = *(const half8*)&vr[(kq ^ lm7) * 8];
        half8 bv1 = *(const half8*)&vr[((4 + kq) ^ lm7) * 8];
#pragma unroll
        for (int cq = 0; cq < 2; ++cq) {
          o[dt][cq] = MFMA16(pa0[cq].h8, bv0, o[dt][cq]);
          o[dt][cq] = MFMA16(pa1[cq].h8, bv1, o[dt][cq]);
        }
      }
#pragma unroll
      for (int cq = 0; cq < 2; ++cq) {
        ol[cq] = MFMA16(pa0[cq].h8, vones, ol[cq]);
        ol[cq] = MFMA16(pa1[cq].h8, vones, ol[cq]);
      }
    }

    // all waves done reading buf cur before iter it+1 overwrites its sibling
    __builtin_amdgcn_s_barrier();
  }

  // epilogue: inv = 1/l lane-local (ol shares O's C-layout rows)
#pragma unroll
  for (int cq = 0; cq < 2; ++cq)
#pragma unroll
    for (int r = 0; r < 4; ++r) {
      const float inv = 1.f / ol[cq][r];
      const size_t base =
          (size_t)(b * T_LEN + qw + cq * 16 + kq * 4 + r) * C_DIM + h * 64;
#pragma unroll
      for (int dt = 0; dt < 4; ++dt)
        y[base + dt * 16 + lm] = (f16)(o[dt][cq][r] * inv);
    }
}

// ---------------------------------------------------------------------------
extern "C" void kernel_launch(void* const* d_in, const int* in_sizes, int n_in,
                              void* d_out, int out_size, void* d_ws, size_t ws_size,
                              hipStream_t stream) {
  const float* x      = (const float*)d_in[0];
  const float* W_attn = (const float*)d_in[1];
  const float* b_attn = (const float*)d_in[2];
  const float* W_proj = (const float*)d_in[3];
  const float* b_proj = (const float*)d_in[4];
  float* out = (float*)d_out;

  const int M = M_ROWS;  // 8192
  auto align256 = [](size_t v) { return (v + 255) & ~(size_t)255; };
  char* ws = (char*)d_ws;
  f16* xh   = (f16*)ws; ws += align256((size_t)M * C_DIM * 2);
  f16* WtA  = (f16*)ws; ws += align256((size_t)THREEC * C_DIM * 2);
  f16* WtP  = (f16*)ws; ws += align256((size_t)C_DIM * C_DIM * 2);
  f16* qkvh = (f16*)ws; ws += align256((size_t)M * THREEC * 2);
  f16* vtg  = (f16*)ws; ws += align256((size_t)B_SZ * H_NUM * 64 * T_LEN * 2);
  f16* yh   = (f16*)ws; ws += align256((size_t)M * C_DIM * 2);

  // fused cast + weight transpose-cast
  prep_kernel<<<CAST_BLOCKS + TP_BX * TP_BY, 256, 0, stream>>>(
      x, xh, W_attn, W_proj, WtA, WtP);

  // qkv = x @ W_attn + b_attn (f16 out), dbuf counted-vmcnt, XCD-swizzled
  gemm_f16_kernel<128, 128, 1, 1><<<dim3(THREEC / 128, M / 128), 256, 0, stream>>>(
      xh, WtA, b_attn, qkvh, nullptr, M, THREEC, C_DIM);

  // V transpose for attention PV B-frags (tau-permuted key columns)
  v_transpose_kernel<<<dim3(B_SZ * H_NUM, T_LEN / 64), 256, 0, stream>>>(qkvh, vtg);

  // y = causal attention (f16 out), 4 waves x 32 q
  attn_kernel<<<dim3(B_SZ * H_NUM, 16), 256, 0, stream>>>(qkvh, vtg, yh);

  // out = y @ W_proj + b_proj (f32 out), dbuf counted-vmcnt, XCD-swizzled
  gemm_f16_kernel<128, 64, 0, 1><<<dim3(C_DIM / 64, M / 128), 256, 0, stream>>>(
      yh, WtP, b_proj, nullptr, out, M, C_DIM, C_DIM);
}

// Round 10
// 187.992 us; speedup vs baseline: 1.0256x; 1.0256x over previous
//
#include <hip/hip_runtime.h>

#define B_SZ   4
#define T_LEN  2048
#define C_DIM  768
#define H_NUM  12
#define THREEC (3 * C_DIM)
#define M_ROWS (B_SZ * T_LEN)          // 8192
#define CAST_N8 (M_ROWS * C_DIM / 8)   // 786432
#define CAST_BLOCKS (CAST_N8 / 256)    // 3072
#define TP_BX ((THREEC + C_DIM) / 32)  // 96
#define TP_BY (C_DIM / 32)             // 24

typedef _Float16 f16;
typedef _Float16 half8 __attribute__((ext_vector_type(8)));
typedef _Float16 half4 __attribute__((ext_vector_type(4)));
typedef __fp16   pk2   __attribute__((ext_vector_type(2)));
typedef float    f32x4 __attribute__((ext_vector_type(4)));

// async global->LDS, 16B/lane; LDS dest = wave-uniform base + lane*16
#define GLD16(gaddr, laddr)                                                         \
  __builtin_amdgcn_global_load_lds(                                                 \
      (const __attribute__((address_space(1))) unsigned int*)(gaddr),               \
      (__attribute__((address_space(3))) unsigned int*)(laddr), 16, 0, 0)
#define MFMA16(a, b, c) __builtin_amdgcn_mfma_f32_16x16x32_f16(a, b, c, 0, 0, 0)

// ---------------------------------------------------------------------------
// Fused prep: [blocks 0..3071] cast x fp32->fp16 (8 elems/thread);
// [blocks 3072..5375] W_attn/W_proj transpose-cast W[K][N] fp32 -> Wt[N][K].
// ---------------------------------------------------------------------------
__global__ __launch_bounds__(256) void prep_kernel(
    const float* __restrict__ x, f16* __restrict__ xh,
    const float* __restrict__ Wa, const float* __restrict__ Wp,
    f16* __restrict__ WtA, f16* __restrict__ WtP) {
  __shared__ f16 tile[32][33];
  const int bid = blockIdx.x;
  if (bid < CAST_BLOCKS) {
    int i = bid * 256 + threadIdx.x;
    const float* s = x + (size_t)i * 8;
    half8 h;
#pragma unroll
    for (int u = 0; u < 8; ++u) h[u] = (f16)s[u];
    *(half8*)(xh + (size_t)i * 8) = h;
    return;   // block-uniform branch; these blocks never reach the barrier
  }
  const int t = bid - CAST_BLOCKS;
  int bx = t % TP_BX;
  const int by = t / TP_BX;
  const float* W; f16* Wt; int N;
  if (bx < THREEC / 32) { W = Wa; Wt = WtA; N = THREEC; }
  else { W = Wp; Wt = WtP; N = C_DIM; bx -= THREEC / 32; }
  const int n0 = bx * 32, k0 = by * 32;
  const int tx = threadIdx.x & 31, ty = threadIdx.x >> 5;
#pragma unroll
  for (int i = 0; i < 4; ++i)
    tile[ty + i * 8][tx] = (f16)W[(size_t)(k0 + ty + i * 8) * N + n0 + tx];
  __syncthreads();
#pragma unroll
  for (int i = 0; i < 4; ++i)
    Wt[(size_t)(n0 + ty + i * 8) * C_DIM + k0 + tx] = tile[tx][ty + i * 8];
}

// ---------------------------------------------------------------------------
// MFMA GEMM: C[M][N] = A[M][K] @ Bt[N][K]^T + bias.  (r6-PROVEN body,
// restored after r9's BK=32 counted-vmcnt regression: that change doubled
// barrier frequency per MFMA -- catalog regime gate: counted vmcnt pays
// inside an 8-phase schedule, not grafted onto a 2-barrier loop. The
// 8-phase 256^2 template itself is wrong for this shape: grid would be
// 288 blocks = 1.125/CU -> makespan tail.)
// BK=64 (32 MFMAs per barrier pair), 4 waves 2x2, global_load_lds staging,
// XOR8 source-side swizzle, XCD-aware chunked block swizzle (nwg % 8 == 0).
// ---------------------------------------------------------------------------
template <int BM, int BN, int OUT_F16, int SWZ>
__global__ __launch_bounds__(256) void gemm_f16_kernel(
    const f16* __restrict__ A, const f16* __restrict__ Bt,
    const float* __restrict__ bias, f16* __restrict__ OutH,
    float* __restrict__ OutF, int M, int N, int K) {
  __shared__ f16 As[BM * 64];
  __shared__ f16 Bs[BN * 64];
  const int tid = threadIdx.x;
  const int lane = tid & 63, wave = tid >> 6;
  const int lm = lane & 15, kq = lane >> 4, lm7 = lm & 7;
  constexpr int MT = BM / 32, NT = BN / 32;
  const int wm = (wave & 1) * (BM / 2), wn = (wave >> 1) * (BN / 2);

  int bx = blockIdx.x, by = blockIdx.y;
  if (SWZ) {
    const int nx = gridDim.x;
    const int lin = by * nx + bx;
    const int cpx = (nx * gridDim.y) >> 3;     // blocks per XCD chunk
    const int swz = (lin & 7) * cpx + (lin >> 3);
    bx = swz % nx;
    by = swz / nx;
  }
  const int row0 = by * BM, col0 = bx * BN;

  f32x4 acc[MT][NT] = {};

  for (int k0 = 0; k0 < K; k0 += 64) {
    __syncthreads();
#pragma unroll
    for (int i = 0; i < BM / 32; ++i) {
      int c = tid + i * 256;
      int r = c >> 3, cc = (c & 7) ^ (r & 7);
      GLD16(&A[(size_t)(row0 + r) * K + k0 + cc * 8],
            &As[(i * 256 + wave * 64) * 8]);
    }
#pragma unroll
    for (int i = 0; i < BN / 32; ++i) {
      int c = tid + i * 256;
      int r = c >> 3, cc = (c & 7) ^ (r & 7);
      GLD16(&Bt[(size_t)(col0 + r) * K + k0 + cc * 8],
            &Bs[(i * 256 + wave * 64) * 8]);
    }
    __syncthreads();
#pragma unroll
    for (int ks = 0; ks < 2; ++ks) {
      const int pos = (ks * 4 + kq);
      half8 af[MT], bf[NT];
#pragma unroll
      for (int t = 0; t < MT; ++t)
        af[t] = *(const half8*)&As[(wm + t * 16 + lm) * 64 + (pos ^ lm7) * 8];
#pragma unroll
      for (int t = 0; t < NT; ++t)
        bf[t] = *(const half8*)&Bs[(wn + t * 16 + lm) * 64 + (pos ^ lm7) * 8];
#pragma unroll
      for (int mt = 0; mt < MT; ++mt)
#pragma unroll
        for (int nt = 0; nt < NT; ++nt)
          acc[mt][nt] = MFMA16(af[mt], bf[nt], acc[mt][nt]);
    }
  }

#pragma unroll
  for (int mt = 0; mt < MT; ++mt) {
    const int row = row0 + wm + mt * 16 + kq * 4;
#pragma unroll
    for (int nt = 0; nt < NT; ++nt) {
      const int col = col0 + wn + nt * 16 + lm;
      const float bv = bias[col];
#pragma unroll
      for (int r = 0; r < 4; ++r) {
        float v = acc[mt][nt][r] + bv;
        if (OUT_F16)
          OutH[(size_t)(row + r) * N + col] = (f16)v;
        else
          OutF[(size_t)(row + r) * N + col] = v;
      }
    }
  }
}

// ---------------------------------------------------------------------------
// V pre-transpose: qkv[B*T][3C] (V slice) -> vt[bh][d=64][T] f16, with the
// tau key-permutation applied within each 64-key block:
//   vt[d][64*blk + m] = V[64*blk + tau(m)][d],
//   tau(m): m bits (hi,kq,j23,j01) -> key = 32*hi + 16*j23 + 4*kq + j01.
// Makes the attention QK^T C-layout directly usable as the PV A-fragment.
// ---------------------------------------------------------------------------
__global__ __launch_bounds__(256) void v_transpose_kernel(
    const f16* __restrict__ qkv, f16* __restrict__ vt) {
  __shared__ f16 tile[64 * 68];
  const int bh = blockIdx.x, b = bh / H_NUM, h = bh % H_NUM;
  const int t0 = blockIdx.y * 64;
  const int tid = threadIdx.x;
#pragma unroll
  for (int i = 0; i < 2; ++i) {
    int c = tid + i * 256;
    int tr = c >> 3, doff = (c & 7) * 8;
    // tau_inv(tr): key bits (hi,j23,kq,j01) -> m = 32*hi + 8*kq + 4*j23 + j01
    int pcol = ((tr >> 5) << 5) | (((tr >> 2) & 3) << 3) |
               (((tr >> 4) & 1) << 2) | (tr & 3);
    half8 v = *(const half8*)&qkv[(size_t)(b * T_LEN + t0 + tr) * THREEC + 2 * C_DIM + h * 64 + doff];
#pragma unroll
    for (int u = 0; u < 8; ++u) tile[(doff + u) * 68 + pcol] = v[u];
  }
  __syncthreads();
#pragma unroll
  for (int i = 0; i < 2; ++i) {
    int c = tid + i * 256;
    int d = c >> 3, toff = (c & 7) * 8;
    half8 v;
#pragma unroll
    for (int u = 0; u < 8; ++u) v[u] = tile[d * 68 + toff + u];
    *(half8*)&vt[((size_t)bh * 64 + d) * T_LEN + t0 + toff] = v;
  }
}

// ---------------------------------------------------------------------------
// MFMA causal flash attention, S^T formulation, XOR-swizzled LDS, no-max
// softmax, l via ones-MFMA, in-register P via tau-permuted V.
// r8-proven: 4 waves x 32 q each (cq=2), dbuf K/V staging with counted
// vmcnt(4), 2 barriers/iter, grid 768 = 3 blocks/CU.
// Round 10: + s_setprio(1) around the compute phase (T5/m191: +4-7% when
// multiple blocks/CU sit at independent phases -- compute-phase waves get
// scheduler priority over other blocks' staging waves. Not applied to the
// GEMMs: m190 showed ~0/negative for barrier-lockstep single-phase blocks).
// ---------------------------------------------------------------------------
__global__ __launch_bounds__(256, 3) void attn_kernel(
    const f16* __restrict__ qkv, const f16* __restrict__ vt,
    f16* __restrict__ y) {
  __shared__ f16 Kt[2][64 * 64];   // [buf][key][d], swizzled
  __shared__ f16 Vt[2][64 * 64];   // [buf][d][key-pos], swizzled, tau-permuted

  const int bh = blockIdx.x, b = bh / H_NUM, h = bh % H_NUM;
  const int yb = blockIdx.y;                 // 0..15, heavy-first
  const int qb = 15 - yb;                    // q-block: rows [qb*128, qb*128+128)
  const int tid = threadIdx.x, lane = tid & 63, wave = tid >> 6;  // wave 0..3
  const int lm = lane & 15, kq = lane >> 4, lm7 = lm & 7;
  const int cw = qb * 2 + (wave >> 1);       // last key-tile this wave needs
  const int qw = qb * 128 + wave * 32;       // wave's 32 q-rows
  const f16 qscale = (f16)(0.125f * 1.44269504f);  // 1/sqrt(D) * log2(e)

  half8 vones;
#pragma unroll
  for (int u = 0; u < 8; ++u) vones[u] = (f16)1.f;

  // Q B-frags: bq[cq][c2], q = qw + cq*16 + lm (pre-scaled). The multiply
  // forces the vmcnt wait HERE, before any staging GLDs are issued.
  half8 bq[2][2];
#pragma unroll
  for (int cq = 0; cq < 2; ++cq)
#pragma unroll
    for (int c2 = 0; c2 < 2; ++c2) {
      half8 v = *(const half8*)&qkv[(size_t)(b * T_LEN + qw + cq * 16 + lm) * THREEC +
                                    h * 64 + c2 * 32 + kq * 8];
      bq[cq][c2] = v * qscale;
    }

  f32x4 o[4][2] = {};   // o[dt][cq]: col = d (lm), row = q (kq*4+r)
  f32x4 ol[2] = {};     // l accumulators, same row layout

  // persistent zero C-operand for the S^T MFMAs (avoid per-tile v_movs)
  f32x4 fz = {};
  asm volatile("" : "+v"(fz));

  // staging geometry: 2 K-chunks + 2 V-chunks per thread (16B each)
  const int srow = tid >> 3;                          // 0..31
  const int scol = ((tid & 7) ^ (srow & 7)) * 8;      // same for srow+32
  const f16* kp = &qkv[(size_t)(b * T_LEN + srow) * THREEC + C_DIM + h * 64 + scol];
  const f16* vp = &vt[((size_t)bh * 64 + srow) * T_LEN + scol];
  const size_t kp2 = (size_t)32 * THREEC;             // +32 rows
  const size_t vp2 = (size_t)32 * T_LEN;

  const int sbase = wave * 512;   // f16 offset of this wave's staging slice

  const int n_tiles = qb * 2 + 2;

  // prologue: stage tile 0 into buf 0 (rows 0..31 then 32..63 of each)
  GLD16(kp, &Kt[0][sbase]);
  GLD16(kp + kp2, &Kt[0][2048 + sbase]);
  GLD16(vp, &Vt[0][sbase]);
  GLD16(vp + vp2, &Vt[0][2048 + sbase]);
  kp += (size_t)64 * THREEC;
  vp += 64;

  for (int it = 0; it < n_tiles; ++it) {
    const int cur = it & 1;
    // stage tile it+1 into buf cur^1 (freed by barrier #2 of iter it-1)
    if (it + 1 < n_tiles) {
      GLD16(kp, &Kt[cur ^ 1][sbase]);
      GLD16(kp + kp2, &Kt[cur ^ 1][2048 + sbase]);
      GLD16(vp, &Vt[cur ^ 1][sbase]);
      GLD16(vp + vp2, &Vt[cur ^ 1][2048 + sbase]);
      kp += (size_t)64 * THREEC;
      vp += 64;
      // wait for tile it's 4 loads (oldest); it+1's 4 stay in flight
      asm volatile("s_waitcnt vmcnt(4)" ::: "memory");
    } else {
      asm volatile("s_waitcnt vmcnt(0)" ::: "memory");
    }
    __builtin_amdgcn_s_barrier();   // all waves' stage(it) visible

    if (it <= cw) {
      __builtin_amdgcn_s_setprio(1);
      // S^T = K @ Q^T : A = K rows (keys), B = Q -> col = q, row = key
      f32x4 s4[4][2];
#pragma unroll
      for (int ct = 0; ct < 4; ++ct) {
        const f16* kr = &Kt[cur][(ct * 16 + lm) * 64];
        half8 ak0 = *(const half8*)&kr[(kq ^ lm7) * 8];
        half8 ak1 = *(const half8*)&kr[((4 + kq) ^ lm7) * 8];
#pragma unroll
        for (int cq = 0; cq < 2; ++cq) {
          f32x4 z = MFMA16(ak0, bq[cq][0], fz);
          s4[ct][cq] = MFMA16(ak1, bq[cq][1], z);
        }
      }
      if (it == cw) {   // diagonal tile: mask keys > q
        const int j0 = it * 64;
#pragma unroll
        for (int ct = 0; ct < 4; ++ct)
#pragma unroll
          for (int cq = 0; cq < 2; ++cq) {
            const int qrow = qw + cq * 16 + lm;
#pragma unroll
            for (int r = 0; r < 4; ++r)
              if (j0 + ct * 16 + kq * 4 + r > qrow) s4[ct][cq][r] = -1e30f;
          }
      }
      // p = exp2(s), packed f32->f16 (RTZ), IN REGISTERS per cq group.
      union { half8 h8; pk2 p2[4]; } pa0[2], pa1[2];
#pragma unroll
      for (int cq = 0; cq < 2; ++cq) {
        pa0[cq].p2[0] = __builtin_amdgcn_cvt_pkrtz(
            __builtin_amdgcn_exp2f(s4[0][cq][0]), __builtin_amdgcn_exp2f(s4[0][cq][1]));
        pa0[cq].p2[1] = __builtin_amdgcn_cvt_pkrtz(
            __builtin_amdgcn_exp2f(s4[0][cq][2]), __builtin_amdgcn_exp2f(s4[0][cq][3]));
        pa0[cq].p2[2] = __builtin_amdgcn_cvt_pkrtz(
            __builtin_amdgcn_exp2f(s4[1][cq][0]), __builtin_amdgcn_exp2f(s4[1][cq][1]));
        pa0[cq].p2[3] = __builtin_amdgcn_cvt_pkrtz(
            __builtin_amdgcn_exp2f(s4[1][cq][2]), __builtin_amdgcn_exp2f(s4[1][cq][3]));
        pa1[cq].p2[0] = __builtin_amdgcn_cvt_pkrtz(
            __builtin_amdgcn_exp2f(s4[2][cq][0]), __builtin_amdgcn_exp2f(s4[2][cq][1]));
        pa1[cq].p2[1] = __builtin_amdgcn_cvt_pkrtz(
            __builtin_amdgcn_exp2f(s4[2][cq][2]), __builtin_amdgcn_exp2f(s4[2][cq][3]));
        pa1[cq].p2[2] = __builtin_amdgcn_cvt_pkrtz(
            __builtin_amdgcn_exp2f(s4[3][cq][0]), __builtin_amdgcn_exp2f(s4[3][cq][1]));
        pa1[cq].p2[3] = __builtin_amdgcn_cvt_pkrtz(
            __builtin_amdgcn_exp2f(s4[3][cq][2]), __builtin_amdgcn_exp2f(s4[3][cq][3]));
      }

      // PV: O += P @ V^T ; l: ol += P @ 1  (V frags shared across cq)
#pragma unroll
      for (int dt = 0; dt < 4; ++dt) {
        const f16* vr = &Vt[cur][(dt * 16 + lm) * 64];
        half8 bv0 = *(const half8*)&vr[(kq ^ lm7) * 8];
        half8 bv1 = *(const half8*)&vr[((4 + kq) ^ lm7) * 8];
#pragma unroll
        for (int cq = 0; cq < 2; ++cq) {
          o[dt][cq] = MFMA16(pa0[cq].h8, bv0, o[dt][cq]);
          o[dt][cq] = MFMA16(pa1[cq].h8, bv1, o[dt][cq]);
        }
      }
#pragma unroll
      for (int cq = 0; cq < 2; ++cq) {
        ol[cq] = MFMA16(pa0[cq].h8, vones, ol[cq]);
        ol[cq] = MFMA16(pa1[cq].h8, vones, ol[cq]);
      }
      __builtin_amdgcn_s_setprio(0);
    }

    // all waves done reading buf cur before iter it+1 overwrites its sibling
    __builtin_amdgcn_s_barrier();
  }

  // epilogue: inv = 1/l lane-local (ol shares O's C-layout rows)
#pragma unroll
  for (int cq = 0; cq < 2; ++cq)
#pragma unroll
    for (int r = 0; r < 4; ++r) {
      const float inv = 1.f / ol[cq][r];
      const size_t base =
          (size_t)(b * T_LEN + qw + cq * 16 + kq * 4 + r) * C_DIM + h * 64;
#pragma unroll
      for (int dt = 0; dt < 4; ++dt)
        y[base + dt * 16 + lm] = (f16)(o[dt][cq][r] * inv);
    }
}

// ---------------------------------------------------------------------------
extern "C" void kernel_launch(void* const* d_in, const int* in_sizes, int n_in,
                              void* d_out, int out_size, void* d_ws, size_t ws_size,
                              hipStream_t stream) {
  const float* x      = (const float*)d_in[0];
  const float* W_attn = (const float*)d_in[1];
  const float* b_attn = (const float*)d_in[2];
  const float* W_proj = (const float*)d_in[3];
  const float* b_proj = (const float*)d_in[4];
  float* out = (float*)d_out;

  const int M = M_ROWS;  // 8192
  auto align256 = [](size_t v) { return (v + 255) & ~(size_t)255; };
  char* ws = (char*)d_ws;
  f16* xh   = (f16*)ws; ws += align256((size_t)M * C_DIM * 2);
  f16* WtA  = (f16*)ws; ws += align256((size_t)THREEC * C_DIM * 2);
  f16* WtP  = (f16*)ws; ws += align256((size_t)C_DIM * C_DIM * 2);
  f16* qkvh = (f16*)ws; ws += align256((size_t)M * THREEC * 2);
  f16* vtg  = (f16*)ws; ws += align256((size_t)B_SZ * H_NUM * 64 * T_LEN * 2);
  f16* yh   = (f16*)ws; ws += align256((size_t)M * C_DIM * 2);

  // fused cast + weight transpose-cast
  prep_kernel<<<CAST_BLOCKS + TP_BX * TP_BY, 256, 0, stream>>>(
      x, xh, W_attn, W_proj, WtA, WtP);

  // qkv = x @ W_attn + b_attn (f16 out), r6-proven body, XCD-swizzled
  gemm_f16_kernel<128, 128, 1, 1><<<dim3(THREEC / 128, M / 128), 256, 0, stream>>>(
      xh, WtA, b_attn, qkvh, nullptr, M, THREEC, C_DIM);

  // V transpose for attention PV B-frags (tau-permuted key columns)
  v_transpose_kernel<<<dim3(B_SZ * H_NUM, T_LEN / 64), 256, 0, stream>>>(qkvh, vtg);

  // y = causal attention (f16 out), 4 waves x 32 q, setprio compute phase
  attn_kernel<<<dim3(B_SZ * H_NUM, 16), 256, 0, stream>>>(qkvh, vtg, yh);

  // out = y @ W_proj + b_proj (f32 out), r6-proven body, XCD-swizzled
  gemm_f16_kernel<128, 64, 0, 1><<<dim3(C_DIM / 64, M / 128), 256, 0, stream>>>(
      yh, WtP, b_proj, nullptr, out, M, C_DIM, C_DIM);
}

// Round 11
// 183.163 us; speedup vs baseline: 1.0527x; 1.0264x over previous
//
#include <hip/hip_runtime.h>

#define B_SZ   4
#define T_LEN  2048
#define C_DIM  768
#define H_NUM  12
#define THREEC (3 * C_DIM)
#define M_ROWS (B_SZ * T_LEN)          // 8192
#define CAST_N8 (M_ROWS * C_DIM / 8)   // 786432
#define CAST_BLOCKS (CAST_N8 / 256)    // 3072
#define TP_BX ((THREEC + C_DIM) / 32)  // 96
#define TP_BY (C_DIM / 32)             // 24

typedef _Float16 f16;
typedef _Float16 half8 __attribute__((ext_vector_type(8)));
typedef _Float16 half4 __attribute__((ext_vector_type(4)));
typedef __fp16   pk2   __attribute__((ext_vector_type(2)));
typedef float    f32x4 __attribute__((ext_vector_type(4)));

// async global->LDS, 16B/lane; LDS dest = wave-uniform base + lane*16
#define GLD16(gaddr, laddr)                                                         \
  __builtin_amdgcn_global_load_lds(                                                 \
      (const __attribute__((address_space(1))) unsigned int*)(gaddr),               \
      (__attribute__((address_space(3))) unsigned int*)(laddr), 16, 0, 0)
#define MFMA16(a, b, c) __builtin_amdgcn_mfma_f32_16x16x32_f16(a, b, c, 0, 0, 0)

// ---------------------------------------------------------------------------
// Fused prep: [blocks 0..3071] cast x fp32->fp16 (8 elems/thread);
// [blocks 3072..5375] W_attn/W_proj transpose-cast W[K][N] fp32 -> Wt[N][K].
// ---------------------------------------------------------------------------
__global__ __launch_bounds__(256) void prep_kernel(
    const float* __restrict__ x, f16* __restrict__ xh,
    const float* __restrict__ Wa, const float* __restrict__ Wp,
    f16* __restrict__ WtA, f16* __restrict__ WtP) {
  __shared__ f16 tile[32][33];
  const int bid = blockIdx.x;
  if (bid < CAST_BLOCKS) {
    int i = bid * 256 + threadIdx.x;
    const float* s = x + (size_t)i * 8;
    half8 h;
#pragma unroll
    for (int u = 0; u < 8; ++u) h[u] = (f16)s[u];
    *(half8*)(xh + (size_t)i * 8) = h;
    return;   // block-uniform branch; these blocks never reach the barrier
  }
  const int t = bid - CAST_BLOCKS;
  int bx = t % TP_BX;
  const int by = t / TP_BX;
  const float* W; f16* Wt; int N;
  if (bx < THREEC / 32) { W = Wa; Wt = WtA; N = THREEC; }
  else { W = Wp; Wt = WtP; N = C_DIM; bx -= THREEC / 32; }
  const int n0 = bx * 32, k0 = by * 32;
  const int tx = threadIdx.x & 31, ty = threadIdx.x >> 5;
#pragma unroll
  for (int i = 0; i < 4; ++i)
    tile[ty + i * 8][tx] = (f16)W[(size_t)(k0 + ty + i * 8) * N + n0 + tx];
  __syncthreads();
#pragma unroll
  for (int i = 0; i < 4; ++i)
    Wt[(size_t)(n0 + ty + i * 8) * C_DIM + k0 + tx] = tile[tx][ty + i * 8];
}

// ---------------------------------------------------------------------------
// MFMA GEMM: C[M][N] = A[M][K] @ Bt[N][K]^T + bias.  (r6-proven body)
// BK=64 (32 MFMAs per barrier pair), 4 waves 2x2, global_load_lds staging,
// XOR8 source-side swizzle, XCD-aware chunked block swizzle (nwg % 8 == 0).
// ---------------------------------------------------------------------------
template <int BM, int BN, int OUT_F16, int SWZ>
__global__ __launch_bounds__(256) void gemm_f16_kernel(
    const f16* __restrict__ A, const f16* __restrict__ Bt,
    const float* __restrict__ bias, f16* __restrict__ OutH,
    float* __restrict__ OutF, int M, int N, int K) {
  __shared__ f16 As[BM * 64];
  __shared__ f16 Bs[BN * 64];
  const int tid = threadIdx.x;
  const int lane = tid & 63, wave = tid >> 6;
  const int lm = lane & 15, kq = lane >> 4, lm7 = lm & 7;
  constexpr int MT = BM / 32, NT = BN / 32;
  const int wm = (wave & 1) * (BM / 2), wn = (wave >> 1) * (BN / 2);

  int bx = blockIdx.x, by = blockIdx.y;
  if (SWZ) {
    const int nx = gridDim.x;
    const int lin = by * nx + bx;
    const int cpx = (nx * gridDim.y) >> 3;     // blocks per XCD chunk
    const int swz = (lin & 7) * cpx + (lin >> 3);
    bx = swz % nx;
    by = swz / nx;
  }
  const int row0 = by * BM, col0 = bx * BN;

  f32x4 acc[MT][NT] = {};

  for (int k0 = 0; k0 < K; k0 += 64) {
    __syncthreads();
#pragma unroll
    for (int i = 0; i < BM / 32; ++i) {
      int c = tid + i * 256;
      int r = c >> 3, cc = (c & 7) ^ (r & 7);
      GLD16(&A[(size_t)(row0 + r) * K + k0 + cc * 8],
            &As[(i * 256 + wave * 64) * 8]);
    }
#pragma unroll
    for (int i = 0; i < BN / 32; ++i) {
      int c = tid + i * 256;
      int r = c >> 3, cc = (c & 7) ^ (r & 7);
      GLD16(&Bt[(size_t)(col0 + r) * K + k0 + cc * 8],
            &Bs[(i * 256 + wave * 64) * 8]);
    }
    __syncthreads();
#pragma unroll
    for (int ks = 0; ks < 2; ++ks) {
      const int pos = (ks * 4 + kq);
      half8 af[MT], bf[NT];
#pragma unroll
      for (int t = 0; t < MT; ++t)
        af[t] = *(const half8*)&As[(wm + t * 16 + lm) * 64 + (pos ^ lm7) * 8];
#pragma unroll
      for (int t = 0; t < NT; ++t)
        bf[t] = *(const half8*)&Bs[(wn + t * 16 + lm) * 64 + (pos ^ lm7) * 8];
#pragma unroll
      for (int mt = 0; mt < MT; ++mt)
#pragma unroll
        for (int nt = 0; nt < NT; ++nt)
          acc[mt][nt] = MFMA16(af[mt], bf[nt], acc[mt][nt]);
    }
  }

#pragma unroll
  for (int mt = 0; mt < MT; ++mt) {
    const int row = row0 + wm + mt * 16 + kq * 4;
#pragma unroll
    for (int nt = 0; nt < NT; ++nt) {
      const int col = col0 + wn + nt * 16 + lm;
      const float bv = bias[col];
#pragma unroll
      for (int r = 0; r < 4; ++r) {
        float v = acc[mt][nt][r] + bv;
        if (OUT_F16)
          OutH[(size_t)(row + r) * N + col] = (f16)v;
        else
          OutF[(size_t)(row + r) * N + col] = v;
      }
    }
  }
}

// ---------------------------------------------------------------------------
// V pre-transpose: qkv[B*T][3C] (V slice) -> vt[bh][d=64][T] f16, with the
// tau key-permutation applied within each 64-key block:
//   vt[d][64*blk + m] = V[64*blk + tau(m)][d],
//   tau(m): m bits (hi,kq,j23,j01) -> key = 32*hi + 16*j23 + 4*kq + j01.
// Makes the attention QK^T C-layout directly usable as the PV A-fragment.
// ---------------------------------------------------------------------------
__global__ __launch_bounds__(256) void v_transpose_kernel(
    const f16* __restrict__ qkv, f16* __restrict__ vt) {
  __shared__ f16 tile[64 * 68];
  const int bh = blockIdx.x, b = bh / H_NUM, h = bh % H_NUM;
  const int t0 = blockIdx.y * 64;
  const int tid = threadIdx.x;
#pragma unroll
  for (int i = 0; i < 2; ++i) {
    int c = tid + i * 256;
    int tr = c >> 3, doff = (c & 7) * 8;
    // tau_inv(tr): key bits (hi,j23,kq,j01) -> m = 32*hi + 8*kq + 4*j23 + j01
    int pcol = ((tr >> 5) << 5) | (((tr >> 2) & 3) << 3) |
               (((tr >> 4) & 1) << 2) | (tr & 3);
    half8 v = *(const half8*)&qkv[(size_t)(b * T_LEN + t0 + tr) * THREEC + 2 * C_DIM + h * 64 + doff];
#pragma unroll
    for (int u = 0; u < 8; ++u) tile[(doff + u) * 68 + pcol] = v[u];
  }
  __syncthreads();
#pragma unroll
  for (int i = 0; i < 2; ++i) {
    int c = tid + i * 256;
    int d = c >> 3, toff = (c & 7) * 8;
    half8 v;
#pragma unroll
    for (int u = 0; u < 8; ++u) v[u] = tile[d * 68 + toff + u];
    *(half8*)&vt[((size_t)bh * 64 + d) * T_LEN + t0 + toff] = v;
  }
}

// ---------------------------------------------------------------------------
// MFMA causal flash attention, S^T formulation, XOR-swizzled LDS, no-max
// softmax, l via ones-MFMA, in-register P via tau-permuted V.
// Round 11: TRIPLE-buffered K/V staging, prefetch depth 2. Grid 768 = 3
// blocks/CU exactly (all co-resident, no backfill) -> kernel time = longest
// block's 32 SERIAL iterations; with depth-1 prefetch only ~600cy of
// compute covered each ~400-900cy L3/HBM load -> exposed latency every
// iteration (r2's perfectly-neutral re-balance is the evidence for
// critical-path-bound). Depth 2: two compute phases cover each load.
// Steady state: tiles it,it+1,it+2 in flight (12 loads) -> vmcnt(8) waits
// exactly for tile it. Tile it+2 reuses tile it-1's buffer, whose readers
// passed iter it-1's trailing barrier before this stage issues. LDS 48KB:
// 160/48 = 3 blocks/CU -- occupancy unchanged (grid-limited anyway).
// ---------------------------------------------------------------------------
__global__ __launch_bounds__(256, 3) void attn_kernel(
    const f16* __restrict__ qkv, const f16* __restrict__ vt,
    f16* __restrict__ y) {
  __shared__ f16 Kt[3][64 * 64];   // [buf][key][d], swizzled
  __shared__ f16 Vt[3][64 * 64];   // [buf][d][key-pos], swizzled, tau-permuted

  const int bh = blockIdx.x, b = bh / H_NUM, h = bh % H_NUM;
  const int yb = blockIdx.y;                 // 0..15, heavy-first
  const int qb = 15 - yb;                    // q-block: rows [qb*128, qb*128+128)
  const int tid = threadIdx.x, lane = tid & 63, wave = tid >> 6;  // wave 0..3
  const int lm = lane & 15, kq = lane >> 4, lm7 = lm & 7;
  const int cw = qb * 2 + (wave >> 1);       // last key-tile this wave needs
  const int qw = qb * 128 + wave * 32;       // wave's 32 q-rows
  const f16 qscale = (f16)(0.125f * 1.44269504f);  // 1/sqrt(D) * log2(e)

  half8 vones;
#pragma unroll
  for (int u = 0; u < 8; ++u) vones[u] = (f16)1.f;

  // Q B-frags: bq[cq][c2], q = qw + cq*16 + lm (pre-scaled). The multiply
  // forces the vmcnt wait HERE, before any staging GLDs are issued.
  half8 bq[2][2];
#pragma unroll
  for (int cq = 0; cq < 2; ++cq)
#pragma unroll
    for (int c2 = 0; c2 < 2; ++c2) {
      half8 v = *(const half8*)&qkv[(size_t)(b * T_LEN + qw + cq * 16 + lm) * THREEC +
                                    h * 64 + c2 * 32 + kq * 8];
      bq[cq][c2] = v * qscale;
    }

  f32x4 o[4][2] = {};   // o[dt][cq]: col = d (lm), row = q (kq*4+r)
  f32x4 ol[2] = {};     // l accumulators, same row layout

  // persistent zero C-operand for the S^T MFMAs (avoid per-tile v_movs)
  f32x4 fz = {};
  asm volatile("" : "+v"(fz));

  // staging geometry: 2 K-chunks + 2 V-chunks per thread (16B each)
  const int srow = tid >> 3;                          // 0..31
  const int scol = ((tid & 7) ^ (srow & 7)) * 8;      // same for srow+32
  const f16* kp = &qkv[(size_t)(b * T_LEN + srow) * THREEC + C_DIM + h * 64 + scol];
  const f16* vp = &vt[((size_t)bh * 64 + srow) * T_LEN + scol];
  const size_t kp2 = (size_t)32 * THREEC;             // +32 rows
  const size_t vp2 = (size_t)32 * T_LEN;

  const int sbase = wave * 512;   // f16 offset of this wave's staging slice

  const int n_tiles = qb * 2 + 2;

  // prologue: stage tiles 0 and 1 into bufs 0 and 1
  GLD16(kp, &Kt[0][sbase]);
  GLD16(kp + kp2, &Kt[0][2048 + sbase]);
  GLD16(vp, &Vt[0][sbase]);
  GLD16(vp + vp2, &Vt[0][2048 + sbase]);
  kp += (size_t)64 * THREEC;
  vp += 64;
  // n_tiles >= 2 always (qb >= 0)
  GLD16(kp, &Kt[1][sbase]);
  GLD16(kp + kp2, &Kt[1][2048 + sbase]);
  GLD16(vp, &Vt[1][sbase]);
  GLD16(vp + vp2, &Vt[1][2048 + sbase]);
  kp += (size_t)64 * THREEC;
  vp += 64;

  int cur = 0;
  for (int it = 0; it < n_tiles; ++it) {
    // stage tile it+2 into tile it-1's buffer (freed: its readers passed
    // iter it-1's trailing barrier, which this thread has also passed)
    if (it + 2 < n_tiles) {
      const int pb = (cur == 0) ? 2 : cur - 1;   // (it+2) % 3
      GLD16(kp, &Kt[pb][sbase]);
      GLD16(kp + kp2, &Kt[pb][2048 + sbase]);
      GLD16(vp, &Vt[pb][sbase]);
      GLD16(vp + vp2, &Vt[pb][2048 + sbase]);
      kp += (size_t)64 * THREEC;
      vp += 64;
      // 12 loads outstanding (it, it+1, it+2); wait for tile it's 4
      asm volatile("s_waitcnt vmcnt(8)" ::: "memory");
    } else if (it + 1 < n_tiles) {
      // 8 outstanding (it, it+1); wait for tile it's 4
      asm volatile("s_waitcnt vmcnt(4)" ::: "memory");
    } else {
      asm volatile("s_waitcnt vmcnt(0)" ::: "memory");
    }
    __builtin_amdgcn_s_barrier();   // all waves' stage(it) visible

    if (it <= cw) {
      __builtin_amdgcn_s_setprio(1);
      // S^T = K @ Q^T : A = K rows (keys), B = Q -> col = q, row = key
      f32x4 s4[4][2];
#pragma unroll
      for (int ct = 0; ct < 4; ++ct) {
        const f16* kr = &Kt[cur][(ct * 16 + lm) * 64];
        half8 ak0 = *(const half8*)&kr[(kq ^ lm7) * 8];
        half8 ak1 = *(const half8*)&kr[((4 + kq) ^ lm7) * 8];
#pragma unroll
        for (int cq = 0; cq < 2; ++cq) {
          f32x4 z = MFMA16(ak0, bq[cq][0], fz);
          s4[ct][cq] = MFMA16(ak1, bq[cq][1], z);
        }
      }
      if (it == cw) {   // diagonal tile: mask keys > q
        const int j0 = it * 64;
#pragma unroll
        for (int ct = 0; ct < 4; ++ct)
#pragma unroll
          for (int cq = 0; cq < 2; ++cq) {
            const int qrow = qw + cq * 16 + lm;
#pragma unroll
            for (int r = 0; r < 4; ++r)
              if (j0 + ct * 16 + kq * 4 + r > qrow) s4[ct][cq][r] = -1e30f;
          }
      }
      // p = exp2(s), packed f32->f16 (RTZ), IN REGISTERS per cq group.
      union { half8 h8; pk2 p2[4]; } pa0[2], pa1[2];
#pragma unroll
      for (int cq = 0; cq < 2; ++cq) {
        pa0[cq].p2[0] = __builtin_amdgcn_cvt_pkrtz(
            __builtin_amdgcn_exp2f(s4[0][cq][0]), __builtin_amdgcn_exp2f(s4[0][cq][1]));
        pa0[cq].p2[1] = __builtin_amdgcn_cvt_pkrtz(
            __builtin_amdgcn_exp2f(s4[0][cq][2]), __builtin_amdgcn_exp2f(s4[0][cq][3]));
        pa0[cq].p2[2] = __builtin_amdgcn_cvt_pkrtz(
            __builtin_amdgcn_exp2f(s4[1][cq][0]), __builtin_amdgcn_exp2f(s4[1][cq][1]));
        pa0[cq].p2[3] = __builtin_amdgcn_cvt_pkrtz(
            __builtin_amdgcn_exp2f(s4[1][cq][2]), __builtin_amdgcn_exp2f(s4[1][cq][3]));
        pa1[cq].p2[0] = __builtin_amdgcn_cvt_pkrtz(
            __builtin_amdgcn_exp2f(s4[2][cq][0]), __builtin_amdgcn_exp2f(s4[2][cq][1]));
        pa1[cq].p2[1] = __builtin_amdgcn_cvt_pkrtz(
            __builtin_amdgcn_exp2f(s4[2][cq][2]), __builtin_amdgcn_exp2f(s4[2][cq][3]));
        pa1[cq].p2[2] = __builtin_amdgcn_cvt_pkrtz(
            __builtin_amdgcn_exp2f(s4[3][cq][0]), __builtin_amdgcn_exp2f(s4[3][cq][1]));
        pa1[cq].p2[3] = __builtin_amdgcn_cvt_pkrtz(
            __builtin_amdgcn_exp2f(s4[3][cq][2]), __builtin_amdgcn_exp2f(s4[3][cq][3]));
      }

      // PV: O += P @ V^T ; l: ol += P @ 1  (V frags shared across cq)
#pragma unroll
      for (int dt = 0; dt < 4; ++dt) {
        const f16* vr = &Vt[cur][(dt * 16 + lm) * 64];
        half8 bv0 = *(const half8*)&vr[(kq ^ lm7) * 8];
        half8 bv1 = *(const half8*)&vr[((4 + kq) ^ lm7) * 8];
#pragma unroll
        for (int cq = 0; cq < 2; ++cq) {
          o[dt][cq] = MFMA16(pa0[cq].h8, bv0, o[dt][cq]);
          o[dt][cq] = MFMA16(pa1[cq].h8, bv1, o[dt][cq]);
        }
      }
#pragma unroll
      for (int cq = 0; cq < 2; ++cq) {
        ol[cq] = MFMA16(pa0[cq].h8, vones, ol[cq]);
        ol[cq] = MFMA16(pa1[cq].h8, vones, ol[cq]);
      }
      __builtin_amdgcn_s_setprio(0);
    }

    // all waves done reading buf cur before a later stage overwrites it
    __builtin_amdgcn_s_barrier();
    cur = (cur == 2) ? 0 : cur + 1;
  }

  // epilogue: inv = 1/l lane-local (ol shares O's C-layout rows)
#pragma unroll
  for (int cq = 0; cq < 2; ++cq)
#pragma unroll
    for (int r = 0; r < 4; ++r) {
      const float inv = 1.f / ol[cq][r];
      const size_t base =
          (size_t)(b * T_LEN + qw + cq * 16 + kq * 4 + r) * C_DIM + h * 64;
#pragma unroll
      for (int dt = 0; dt < 4; ++dt)
        y[base + dt * 16 + lm] = (f16)(o[dt][cq][r] * inv);
    }
}

// ---------------------------------------------------------------------------
extern "C" void kernel_launch(void* const* d_in, const int* in_sizes, int n_in,
                              void* d_out, int out_size, void* d_ws, size_t ws_size,
                              hipStream_t stream) {
  const float* x      = (const float*)d_in[0];
  const float* W_attn = (const float*)d_in[1];
  const float* b_attn = (const float*)d_in[2];
  const float* W_proj = (const float*)d_in[3];
  const float* b_proj = (const float*)d_in[4];
  float* out = (float*)d_out;

  const int M = M_ROWS;  // 8192
  auto align256 = [](size_t v) { return (v + 255) & ~(size_t)255; };
  char* ws = (char*)d_ws;
  f16* xh   = (f16*)ws; ws += align256((size_t)M * C_DIM * 2);
  f16* WtA  = (f16*)ws; ws += align256((size_t)THREEC * C_DIM * 2);
  f16* WtP  = (f16*)ws; ws += align256((size_t)C_DIM * C_DIM * 2);
  f16* qkvh = (f16*)ws; ws += align256((size_t)M * THREEC * 2);
  f16* vtg  = (f16*)ws; ws += align256((size_t)B_SZ * H_NUM * 64 * T_LEN * 2);
  f16* yh   = (f16*)ws; ws += align256((size_t)M * C_DIM * 2);

  // fused cast + weight transpose-cast
  prep_kernel<<<CAST_BLOCKS + TP_BX * TP_BY, 256, 0, stream>>>(
      x, xh, W_attn, W_proj, WtA, WtP);

  // qkv = x @ W_attn + b_attn (f16 out), r6-proven body, XCD-swizzled
  gemm_f16_kernel<128, 128, 1, 1><<<dim3(THREEC / 128, M / 128), 256, 0, stream>>>(
      xh, WtA, b_attn, qkvh, nullptr, M, THREEC, C_DIM);

  // V transpose for attention PV B-frags (tau-permuted key columns)
  v_transpose_kernel<<<dim3(B_SZ * H_NUM, T_LEN / 64), 256, 0, stream>>>(qkvh, vtg);

  // y = causal attention (f16 out), 4 waves x 32 q, depth-2 prefetch
  attn_kernel<<<dim3(B_SZ * H_NUM, 16), 256, 0, stream>>>(qkvh, vtg, yh);

  // out = y @ W_proj + b_proj (f32 out), r6-proven body, XCD-swizzled
  gemm_f16_kernel<128, 64, 0, 1><<<dim3(C_DIM / 64, M / 128), 256, 0, stream>>>(
      yh, WtP, b_proj, nullptr, out, M, C_DIM, C_DIM);
}